// Round 18
// baseline (228.101 us; speedup 1.0000x reference)
//
#include <hip/hip_runtime.h>
#include <hip/hip_fp16.h>

#define S_LEN  1000
#define NH     8
#define DH     64
#define LOG2E  1.44269504088896f
#define KSCL   (0.125f*LOG2E)

typedef __attribute__((ext_vector_type(8))) _Float16 f16x8;
typedef __attribute__((ext_vector_type(4))) float    f32x4;

// may-alias access types for the overlaid LDS regions (same-address ordering
// preserved by the compiler; HW DS is per-wave in-order)
typedef _Float16           __attribute__((may_alias)) f16a;
typedef float              __attribute__((may_alias)) f32a;
typedef unsigned long long __attribute__((may_alias)) u64a;
typedef unsigned int       __attribute__((ext_vector_type(4), may_alias)) u32x4a;
typedef _Float16           __attribute__((ext_vector_type(8), may_alias)) f16x8a;

// ---- workspace (f16 element offsets), total < 16 MiB ----
// Kh  [64 bh][1000 k][64 d]   (K * 0.125 * log2e)
// VTh [64 bh][64 d][1000 k]
// RKC [1128 j][64 d]          RkE[cidx(j)] * log2e
// RVC [64 d][1128 j]          RvE[cidx(j)] transposed
#define KH_OFF  0ull
#define VT_OFF  4096000ull
#define RKC_OFF 8192000ull
#define RVC_OFF 8264192ull

// ---- LDS: per-wave 6144 B (2 waves/block = 12288 B) ----
//  +0    (4096B): S2row [16 q][256B] f16 (bias rows) -> overlaid by W [16 q][256B]
//  +4096 (2048B): P [16 q][128B] f16
#define WAVE_LDS 6144

static __device__ __forceinline__ int cidx(int g){
  int r = g % S_LEN; if (r < 0) r += S_LEN;
  int r2 = S_LEN - r;
  return r < r2 ? r : r2;
}

#define F4LD(dst, ptr, i) { float4 _t = reinterpret_cast<const float4*>(ptr)[i]; \
  (dst)[4*(i)]=_t.x; (dst)[4*(i)+1]=_t.y; (dst)[4*(i)+2]=_t.z; (dst)[4*(i)+3]=_t.w; }

// ============ prologue 1: Kh (scaled f16) + VTh (f16 transpose) ============
__global__ __launch_bounds__(256)
void p_kv(const float* __restrict__ Kg, const float* __restrict__ Vg,
          _Float16* __restrict__ ws)
{
  __shared__ float tile[64][65];
  const int blk = blockIdx.x;
  const int bh  = blk >> 4;
  const int c   = blk & 15;
  const int b = bh >> 3, h = bh & 7;
  const int t = threadIdx.x;
  const int k0 = c*64;
  {
    const int kb = t >> 2, dq = (t & 3)*16;
    const int k = k0 + kb;
    float vv[16];
    if (k < S_LEN) {
      const float* srcv = Vg + ((size_t)(b*S_LEN + k))*512 + h*DH + dq;
      const float* srck = Kg + ((size_t)(b*S_LEN + k))*512 + h*DH + dq;
      float vk[16];
#pragma unroll
      for (int i=0;i<4;i++){ F4LD(vv, srcv, i); F4LD(vk, srck, i); }
      union { uint4 q[2]; _Float16 h[16]; } o;
#pragma unroll
      for (int i=0;i<16;i++) o.h[i] = (_Float16)(vk[i]*KSCL);
      _Float16* dst = ws + KH_OFF + ((size_t)bh*S_LEN + k)*64 + dq;
      reinterpret_cast<uint4*>(dst)[0] = o.q[0];
      reinterpret_cast<uint4*>(dst)[1] = o.q[1];
    } else {
#pragma unroll
      for (int i=0;i<16;i++) vv[i] = 0.f;
    }
#pragma unroll
    for (int i=0;i<16;i++) tile[kb][dq+i] = vv[i];
  }
  __syncthreads();
  {
    const int d = t >> 2, kq = (t & 3)*16;
    _Float16* dst = ws + VT_OFF + ((size_t)(bh*64 + d))*S_LEN + k0 + kq;
    if (k0 + kq + 15 < S_LEN) {
      union { uint4 q[2]; _Float16 h[16]; } o;
#pragma unroll
      for (int i=0;i<16;i++) o.h[i] = (_Float16)tile[kq+i][d];
      reinterpret_cast<uint4*>(dst)[0] = o.q[0];
      reinterpret_cast<uint4*>(dst)[1] = o.q[1];
    } else {
#pragma unroll
      for (int i=0;i<16;i++)
        if (k0 + kq + i < S_LEN) dst[i] = (_Float16)tile[kq+i][d];
    }
  }
}

// ============ prologue 2: circular tables RKC (x log2e) / RVC ============
__global__ __launch_bounds__(256)
void p_rel(const float* __restrict__ RKg, const float* __restrict__ RVg,
           _Float16* __restrict__ ws)
{
  const int j  = blockIdx.x*64 + (threadIdx.x >> 2);
  const int dq = (threadIdx.x & 3)*16;
  if (j >= 1128) return;
  const int row = cidx(j);
  float vk[16], vv[16];
  const float* sk = RKg + (size_t)row*DH + dq;
  const float* sv = RVg + (size_t)row*DH + dq;
#pragma unroll
  for (int i=0;i<4;i++){ F4LD(vk, sk, i); F4LD(vv, sv, i); }
  {
    union { uint4 q[2]; _Float16 h[16]; } o;
#pragma unroll
    for (int i=0;i<16;i++) o.h[i] = (_Float16)(vk[i]*LOG2E);
    _Float16* dst = ws + RKC_OFF + (size_t)j*64 + dq;
    reinterpret_cast<uint4*>(dst)[0] = o.q[0];
    reinterpret_cast<uint4*>(dst)[1] = o.q[1];
  }
#pragma unroll
  for (int i=0;i<16;i++)
    ws[RVC_OFF + (size_t)(dq+i)*1128 + j] = (_Float16)vv[i];
}

// ============ main: 2-wave kt-split, cross-iteration K+R prefetch @ (128,2) ============
__global__ __launch_bounds__(128, 2)
void cra_attn(const float* __restrict__ Qg, const _Float16* __restrict__ ws,
              float* __restrict__ Og)
{
  __shared__ char sm[2*WAVE_LDS];

  const int tid  = threadIdx.x;
  const int lane = tid & 63;
  const int w    = __builtin_amdgcn_readfirstlane(tid >> 6);
  const int lo   = lane & 15;      // this lane's q row
  const int hi   = lane >> 4;
  char* const smw = sm + w*WAVE_LDS;
  const unsigned swz = (((unsigned)lo)&7u)<<4;

  // loop-invariant per-lane element offsets
  const int laneK = lo*64    + hi*8;   // Kh/RKC rows (stride 64)
  const int laneV = lo*S_LEN + hi*8;   // VTh rows (stride 1000)
  const int laneR = lo*1128  + hi*8;   // RVC rows (stride 1128)

  // XCD-aware bijective swizzle: 4032 = 8 * 504
  const int bid2 = (blockIdx.x & 7) * 504 + (blockIdx.x >> 3);
  const int bh = bid2 / 63;
  const int qs = bid2 - bh*63;     // 16-row q strip, 0..62
  const int b = bh >> 3, h = bh & 7;
  const int q0 = qs * 16;

  const _Float16* const Kh  = ws + KH_OFF + (size_t)bh*S_LEN*64;
  const _Float16* const VTh = ws + VT_OFF + (size_t)bh*64*S_LEN;
  const _Float16* const RKC = ws + RKC_OFF;
  const _Float16* const RVC = ws + RVC_OFF;

  // ---- Q fragments (f16), row = lo ----
  f16x8 aq[2];
  {
    int qr = q0 + lo; if (qr > S_LEN-1) qr = S_LEN-1;
    const float* qsrc = Qg + ((size_t)b*S_LEN + qr)*512 + h*DH;
#pragma unroll
    for (int kk=0;kk<2;kk++){
      float v[8];
      F4LD(v, qsrc + hi*8 + 32*kk, 0);
      F4LD(v, qsrc + hi*8 + 32*kk, 1);
      union { f16x8 f; _Float16 h[8]; } c;
#pragma unroll
      for (int j=0;j<8;j++) c.h[j] = (_Float16)v[j];
      aq[kk] = c.f;
    }
  }

  f32x4 acc[4];
#pragma unroll
  for (int i=0;i<4;i++) acc[i] = (f32x4){0.f,0.f,0.f,0.f};
  float m_run = -1e30f, l_run = 0.f;   // per-lane scalars (q = lo), base-2 units

  const int ktbase = w*8;

  // ---- double-buffered K/R fragment registers (parity-indexed, unrolled) ----
  f16x8 Kb[2][8], Rb[2][10];
  {
    const _Float16* kp = Kh + (size_t)(ktbase*64)*64 + laneK;
#pragma unroll
    for (int i=0;i<8;i++)
      Kb[0][i] = *(const f16x8*)(kp + (i>>1)*1024 + (i&1)*32);
    int jv0 = q0 - ktbase*64 - 63;
    if (jv0 < 0) jv0 += S_LEN;
    if (jv0 < 0) jv0 += S_LEN;
    const _Float16* rp = RKC + (size_t)jv0*64 + laneK;
#pragma unroll
    for (int i=0;i<10;i++)
      Rb[0][i] = *(const f16x8*)(rp + (i>>1)*1024 + (i&1)*32);
  }

#pragma unroll
  for (int t8=0; t8<8; ++t8){
    const int cur = t8 & 1, nxt = cur ^ 1;
    const int kt = ktbase + t8;
    const int k0 = kt*64;
    int jv = q0 - kt*64 - 63;
    if (jv < 0) jv += S_LEN;
    if (jv < 0) jv += S_LEN;
    const int sh  = jv & 7;
    const int jv8 = jv - sh;

    // ---- C1 (swapped): sf[fc] = K_fc * Q^T (Kb[cur] prefetched last iter) ----
    f32x4 sf[4];
#pragma unroll
    for (int fc=0;fc<4;fc++){
      sf[fc] = (f32x4){0.f,0.f,0.f,0.f};
      sf[fc] = __builtin_amdgcn_mfma_f32_16x16x32_f16(Kb[cur][fc*2+0], aq[0], sf[fc], 0,0,0);
      sf[fc] = __builtin_amdgcn_mfma_f32_16x16x32_f16(Kb[cur][fc*2+1], aq[1], sf[fc], 0,0,0);
    }
    // ---- S2 (swapped): C[dgl][q]; store rows [q=lo][dgl] as u64 ----
#pragma unroll
    for (int dc=0;dc<5;dc++){
      f32x4 s2 = (f32x4){0.f,0.f,0.f,0.f};
      s2 = __builtin_amdgcn_mfma_f32_16x16x32_f16(Rb[cur][dc*2+0], aq[0], s2, 0,0,0);
      s2 = __builtin_amdgcn_mfma_f32_16x16x32_f16(Rb[cur][dc*2+1], aq[1], s2, 0,0,0);
      union { unsigned long long u; _Float16 h[4]; } tt;
#pragma unroll
      for (int r=0;r<4;r++) tt.h[r] = (_Float16)s2[r];
      *(u64a*)(smw + (unsigned)(lo*256) + (((unsigned)(dc*32 + hi*8)) ^ swz)) = tt.u;
    }

    // ---- cross-iteration prefetch: next K+R batches (hide under softmax) ----
    if (t8 < 7){
      const int k0n = (kt+1)*64;
      int jvn = q0 - (kt+1)*64 - 63;
      if (jvn < 0) jvn += S_LEN;
      if (jvn < 0) jvn += S_LEN;
      const _Float16* kpn = Kh + (size_t)k0n*64 + laneK;
#pragma unroll
      for (int i=0;i<8;i++)
        Kb[nxt][i] = *(const f16x8*)(kpn + (i>>1)*1024 + (i&1)*32);
      const _Float16* rpn = RKC + (size_t)jvn*64 + laneK;
#pragma unroll
      for (int i=0;i<10;i++)
        Rb[nxt][i] = *(const f16x8*)(rpn + (i>>1)*1024 + (i&1)*32);
    }

    // ---- T14 prefetch: PV's 8 V-frags issue now, consumed after softmax ----
    f16x8 bv[8];
    {
      const _Float16* vp = VTh + k0 + laneV;
#pragma unroll
      for (int i=0;i<8;i++)
        bv[i] = *(const f16x8*)(vp + (i>>1)*(16*S_LEN) + (i&1)*32);
    }

    // ---- bias add (same-wave LDS readback; may_alias keeps order vs stores) ----
    float mx = -1e30f;
#pragma unroll
    for (int fc=0;fc<4;fc++){
#pragma unroll
      for (int r=0;r<4;r++){
        const int kp2 = fc*16 + hi*4 + r;
        const int dgl = lo - kp2 + 63;
        const f16a hb = *(const f16a*)(smw + (unsigned)(lo*256) + (((unsigned)(dgl*2)) ^ swz));
        float v = sf[fc][r] + (float)hb;
        if (k0 + kp2 >= S_LEN) v = -1e30f;
        sf[fc][r] = v;
        mx = fmaxf(mx, v);
      }
    }

    // ---- W zero-fill (4KB); ordered after the bias reads (may-alias) ----
    {
      const u32x4a z = {0u,0u,0u,0u};
#pragma unroll
      for (int i=0;i<4;i++)
        *(u32x4a*)(smw + (unsigned)(i*1024 + lane*16)) = z;
    }

    // ---- softmax (base-2, lane-local row q=lo); prefetches in flight under this ----
    mx = fmaxf(mx, __shfl_xor(mx,16));
    mx = fmaxf(mx, __shfl_xor(mx,32));
    const float mnew = fmaxf(m_run, mx);
    const float rr = exp2f(m_run - mnew);
    m_run = mnew;
    float sum = 0.f;
#pragma unroll
    for (int fc=0;fc<4;fc++){
#pragma unroll
      for (int r=0;r<4;r++){
        const float pv = exp2f(sf[fc][r] - mnew);
        sf[fc][r] = pv; sum += pv;
      }
    }
    sum += __shfl_xor(sum,16);
    sum += __shfl_xor(sum,32);
    l_run = l_run*rr + sum;

    // acc rescale: need rr at q = 4*hi + r
    {
      float rs0 = __shfl(rr, hi*4+0);
      float rs1 = __shfl(rr, hi*4+1);
      float rs2 = __shfl(rr, hi*4+2);
      float rs3 = __shfl(rr, hi*4+3);
#pragma unroll
      for (int fc=0;fc<4;fc++){
        acc[fc][0]*=rs0; acc[fc][1]*=rs1; acc[fc][2]*=rs2; acc[fc][3]*=rs3;
      }
    }

    // ---- scatter: P u64 rows, W scalar banded ----
#pragma unroll
    for (int fc=0;fc<4;fc++){
      union { unsigned long long u; _Float16 hh[4]; } tp;
#pragma unroll
      for (int r=0;r<4;r++) tp.hh[r] = (_Float16)sf[fc][r];
      *(u64a*)(smw + 4096u + (unsigned)(lo*128) + (((unsigned)(fc*32 + hi*8)) ^ swz)) = tp.u;
#pragma unroll
      for (int r=0;r<4;r++){
        const int kp2 = fc*16 + hi*4 + r;
        const int dgp = lo - kp2 + 63 + sh;
        *(f16a*)(smw + (unsigned)(lo*256) + (((unsigned)(dgp*2)) ^ swz)) = tp.hh[r];
      }
    }

    // ---- C4a: acc += P @ V^T (bv prefetched) ----
    f16x8 ap[2];
#pragma unroll
    for (int kk=0;kk<2;kk++)
      ap[kk] = *(const f16x8a*)(smw + 4096u + (unsigned)(lo*128) + (((unsigned)(kk*64 + hi*16)) ^ swz));
#pragma unroll
    for (int kk=0;kk<2;kk++){
#pragma unroll
      for (int fc=0;fc<4;fc++)
        acc[fc] = __builtin_amdgcn_mfma_f32_16x16x32_f16(ap[kk], bv[fc*2+kk], acc[fc], 0,0,0);
    }

    // ---- C4b: acc += W @ RvE^T (batch 4 frags per kk) ----
    const _Float16* rvp = RVC + jv8 + laneR;
#pragma unroll
    for (int kk=0;kk<3;kk++){
      f16x8 bw[4];
#pragma unroll
      for (int fc=0;fc<4;fc++)
        bw[fc] = *(const f16x8*)(rvp + fc*(16*1128) + kk*32);
      f16x8 aw = *(const f16x8a*)(smw + (unsigned)(lo*256) + (((unsigned)(kk*64 + hi*16)) ^ swz));
#pragma unroll
      for (int fc=0;fc<4;fc++)
        acc[fc] = __builtin_amdgcn_mfma_f32_16x16x32_f16(aw, bw[fc], acc[fc], 0,0,0);
    }
  }

  // ---- merge the two kt-halves ----
  if (w == 1){
#pragma unroll
    for (int fc=0; fc<4; fc++)
#pragma unroll
      for (int r=0; r<4; r++)
        *(f32a*)(sm + WAVE_LDS + (unsigned)((hi*4+r)*256 + (fc*16+lo)*4)) = acc[fc][r];
    if (hi == 0){
      *(f32a*)(sm + WAVE_LDS + 4096u + (unsigned)(lo*8))     = m_run;
      *(f32a*)(sm + WAVE_LDS + 4096u + (unsigned)(lo*8 + 4)) = l_run;
    }
  }
  __syncthreads();
  if (w == 0){
    const float m1 = *(const f32a*)(sm + WAVE_LDS + 4096u + (unsigned)(lo*8));
    const float l1 = *(const f32a*)(sm + WAVE_LDS + 4096u + (unsigned)(lo*8 + 4));
    const float mm = fmaxf(m_run, m1);
    const float e0 = exp2f(m_run - mm);
    const float e1 = exp2f(m1 - mm);
    const float inv = 1.f / (l_run*e0 + l1*e1);
    const float f0 = e0*inv, f1 = e1*inv;
    float f0b[4], f1b[4];
#pragma unroll
    for (int r=0;r<4;r++){
      f0b[r] = __shfl(f0, hi*4+r);
      f1b[r] = __shfl(f1, hi*4+r);
    }
#pragma unroll
    for (int fc=0; fc<4; fc++)
#pragma unroll
      for (int r=0; r<4; r++){
        const int q = q0 + hi*4 + r;
        const float a1 = *(const f32a*)(sm + WAVE_LDS + (unsigned)((hi*4+r)*256 + (fc*16+lo)*4));
        if (q < S_LEN)
          Og[((size_t)b*S_LEN + q)*512 + h*DH + fc*16 + lo] =
              acc[fc][r]*f0b[r] + a1*f1b[r];
      }
  }
}

extern "C" void kernel_launch(void* const* d_in, const int* in_sizes, int n_in,
                              void* d_out, int out_size, void* d_ws, size_t ws_size,
                              hipStream_t stream) {
  (void)in_sizes; (void)n_in; (void)out_size; (void)ws_size;
  const float* Q  = (const float*)d_in[0];
  const float* K  = (const float*)d_in[1];
  const float* V  = (const float*)d_in[2];
  const float* RK = (const float*)d_in[3];
  const float* RV = (const float*)d_in[4];
  float* O = (float*)d_out;
  _Float16* ws = (_Float16*)d_ws;

  p_kv <<<dim3(1024), dim3(256), 0, stream>>>(K, V, ws);
  p_rel<<<dim3(18),   dim3(256), 0, stream>>>(RK, RV, ws);
  cra_attn<<<dim3(4032), dim3(128), 0, stream>>>(Q, ws, O);
}

// Round 19
// 198.783 us; speedup vs baseline: 1.1475x; 1.1475x over previous
//
#include <hip/hip_runtime.h>
#include <hip/hip_fp16.h>

#define S_LEN  1000
#define NH     8
#define DH     64
#define LOG2E  1.44269504088896f
#define KSCL   (0.125f*LOG2E)

typedef __attribute__((ext_vector_type(8))) _Float16 f16x8;
typedef __attribute__((ext_vector_type(4))) float    f32x4;

// may-alias access types for the overlaid LDS regions (same-address ordering
// preserved by the compiler; HW DS is per-wave in-order)
typedef _Float16           __attribute__((may_alias)) f16a;
typedef float              __attribute__((may_alias)) f32a;
typedef unsigned long long __attribute__((may_alias)) u64a;
typedef unsigned int       __attribute__((ext_vector_type(4), may_alias)) u32x4a;
typedef _Float16           __attribute__((ext_vector_type(8), may_alias)) f16x8a;

// ---- workspace (f16 element offsets), total < 16 MiB ----
// Kh  [64 bh][1000 k][64 d]   (K * 0.125 * log2e)
// VTh [64 bh][64 d][1000 k]
// RKC [1128 j][64 d]          RkE[cidx(j)] * log2e
// RVC [64 d][1128 j]          RvE[cidx(j)] transposed
#define KH_OFF  0ull
#define VT_OFF  4096000ull
#define RKC_OFF 8192000ull
#define RVC_OFF 8264192ull

// ---- LDS: per-wave 6144 B (4 waves/block = 24576 B) ----
//  +0    (4096B): S2row [16 q][256B] f16 (bias rows) -> overlaid by W [16 q][256B]
//  +4096 (2048B): P [16 q][128B] f16
// merge: wk==1 wave stores acc/m/l into its OWN region after its loop ends.
#define WAVE_LDS 6144

static __device__ __forceinline__ int cidx(int g){
  int r = g % S_LEN; if (r < 0) r += S_LEN;
  int r2 = S_LEN - r;
  return r < r2 ? r : r2;
}

#define F4LD(dst, ptr, i) { float4 _t = reinterpret_cast<const float4*>(ptr)[i]; \
  (dst)[4*(i)]=_t.x; (dst)[4*(i)+1]=_t.y; (dst)[4*(i)+2]=_t.z; (dst)[4*(i)+3]=_t.w; }

// ============ prologue 1: Kh (scaled f16) + VTh (f16 transpose) ============
__global__ __launch_bounds__(256)
void p_kv(const float* __restrict__ Kg, const float* __restrict__ Vg,
          _Float16* __restrict__ ws)
{
  __shared__ float tile[64][65];
  const int blk = blockIdx.x;
  const int bh  = blk >> 4;
  const int c   = blk & 15;
  const int b = bh >> 3, h = bh & 7;
  const int t = threadIdx.x;
  const int k0 = c*64;
  {
    const int kb = t >> 2, dq = (t & 3)*16;
    const int k = k0 + kb;
    float vv[16];
    if (k < S_LEN) {
      const float* srcv = Vg + ((size_t)(b*S_LEN + k))*512 + h*DH + dq;
      const float* srck = Kg + ((size_t)(b*S_LEN + k))*512 + h*DH + dq;
      float vk[16];
#pragma unroll
      for (int i=0;i<4;i++){ F4LD(vv, srcv, i); F4LD(vk, srck, i); }
      union { uint4 q[2]; _Float16 h[16]; } o;
#pragma unroll
      for (int i=0;i<16;i++) o.h[i] = (_Float16)(vk[i]*KSCL);
      _Float16* dst = ws + KH_OFF + ((size_t)bh*S_LEN + k)*64 + dq;
      reinterpret_cast<uint4*>(dst)[0] = o.q[0];
      reinterpret_cast<uint4*>(dst)[1] = o.q[1];
    } else {
#pragma unroll
      for (int i=0;i<16;i++) vv[i] = 0.f;
    }
#pragma unroll
    for (int i=0;i<16;i++) tile[kb][dq+i] = vv[i];
  }
  __syncthreads();
  {
    const int d = t >> 2, kq = (t & 3)*16;
    _Float16* dst = ws + VT_OFF + ((size_t)(bh*64 + d))*S_LEN + k0 + kq;
    if (k0 + kq + 15 < S_LEN) {
      union { uint4 q[2]; _Float16 h[16]; } o;
#pragma unroll
      for (int i=0;i<16;i++) o.h[i] = (_Float16)tile[kq+i][d];
      reinterpret_cast<uint4*>(dst)[0] = o.q[0];
      reinterpret_cast<uint4*>(dst)[1] = o.q[1];
    } else {
#pragma unroll
      for (int i=0;i<16;i++)
        if (k0 + kq + i < S_LEN) dst[i] = (_Float16)tile[kq+i][d];
    }
  }
}

// ============ prologue 2: circular tables RKC (x log2e) / RVC ============
__global__ __launch_bounds__(256)
void p_rel(const float* __restrict__ RKg, const float* __restrict__ RVg,
           _Float16* __restrict__ ws)
{
  const int j  = blockIdx.x*64 + (threadIdx.x >> 2);
  const int dq = (threadIdx.x & 3)*16;
  if (j >= 1128) return;
  const int row = cidx(j);
  float vk[16], vv[16];
  const float* sk = RKg + (size_t)row*DH + dq;
  const float* sv = RVg + (size_t)row*DH + dq;
#pragma unroll
  for (int i=0;i<4;i++){ F4LD(vk, sk, i); F4LD(vv, sv, i); }
  {
    union { uint4 q[2]; _Float16 h[16]; } o;
#pragma unroll
    for (int i=0;i<16;i++) o.h[i] = (_Float16)(vk[i]*LOG2E);
    _Float16* dst = ws + RKC_OFF + (size_t)j*64 + dq;
    reinterpret_cast<uint4*>(dst)[0] = o.q[0];
    reinterpret_cast<uint4*>(dst)[1] = o.q[1];
  }
#pragma unroll
  for (int i=0;i<16;i++)
    ws[RVC_OFF + (size_t)(dq+i)*1128 + j] = (_Float16)vv[i];
}

// ============ main: 4-wave blocks (2 q-substrips x kt-split), measured optimum ============
__global__ __launch_bounds__(256, 3)
void cra_attn(const float* __restrict__ Qg, const _Float16* __restrict__ ws,
              float* __restrict__ Og)
{
  __shared__ char sm[4*WAVE_LDS];

  const int tid  = threadIdx.x;
  const int lane = tid & 63;
  const int w    = __builtin_amdgcn_readfirstlane(tid >> 6);  // 0..3
  const int wq   = w >> 1;         // q-substrip within pair
  const int wk   = w & 1;          // kt half: 0 -> kt 0-7, 1 -> kt 8-15
  const int lo   = lane & 15;      // this lane's q row
  const int hi   = lane >> 4;
  char* const smw = sm + w*WAVE_LDS;
  const unsigned swz = (((unsigned)lo)&7u)<<4;

  // loop-invariant per-lane element offsets
  const int laneK = lo*64    + hi*8;   // Kh/RKC rows (stride 64)
  const int laneV = lo*S_LEN + hi*8;   // VTh rows (stride 1000)
  const int laneR = lo*1128  + hi*8;   // RVC rows (stride 1128)

  // XCD-aware bijective swizzle: 2048 = 8 * 256 -> batch b per XCD
  const int bid2 = (blockIdx.x & 7) * 256 + (blockIdx.x >> 3);
  const int bh = bid2 >> 5;
  const int qs = bid2 & 31;        // 32-row q pair-strip, 0..31
  const int b = bh >> 3, h = bh & 7;
  const int q0 = qs*32 + wq*16;    // this wave's 16-row strip

  const _Float16* const Kh  = ws + KH_OFF + (size_t)bh*S_LEN*64;
  const _Float16* const VTh = ws + VT_OFF + (size_t)bh*64*S_LEN;
  const _Float16* const RKC = ws + RKC_OFF;
  const _Float16* const RVC = ws + RVC_OFF;

  // ---- Q fragments (f16), row = lo ----
  f16x8 aq[2];
  {
    int qr = q0 + lo; if (qr > S_LEN-1) qr = S_LEN-1;
    const float* qsrc = Qg + ((size_t)b*S_LEN + qr)*512 + h*DH;
#pragma unroll
    for (int kk=0;kk<2;kk++){
      float v[8];
      F4LD(v, qsrc + hi*8 + 32*kk, 0);
      F4LD(v, qsrc + hi*8 + 32*kk, 1);
      union { f16x8 f; _Float16 h[8]; } c;
#pragma unroll
      for (int j=0;j<8;j++) c.h[j] = (_Float16)v[j];
      aq[kk] = c.f;
    }
  }

  f32x4 acc[4];
#pragma unroll
  for (int i=0;i<4;i++) acc[i] = (f32x4){0.f,0.f,0.f,0.f};
  float m_run = -1e30f, l_run = 0.f;   // per-lane scalars (q = lo), base-2 units

  const int ktbase = wk*8;
#pragma unroll
  for (int t8=0; t8<8; ++t8){
    const int kt = ktbase + t8;
    const int k0 = kt*64;
    int jv = q0 - kt*64 - 63;
    if (jv < 0) jv += S_LEN;
    if (jv < 0) jv += S_LEN;
    const int sh  = jv & 7;
    const int jv8 = jv - sh;

    // ---- batch-load C1's 8 K-frags ----
    f16x8 bfr[10];
    const _Float16* kp = Kh + (size_t)k0*64 + laneK;
#pragma unroll
    for (int i=0;i<8;i++)
      bfr[i] = *(const f16x8*)(kp + (i>>1)*1024 + (i&1)*32);

    // ---- C1 (swapped): sf[fc] = K_fc * Q^T -> lane: q=lo, k'=fc*16+4hi+reg ----
    f32x4 sf[4];
#pragma unroll
    for (int fc=0;fc<4;fc++){
      sf[fc] = (f32x4){0.f,0.f,0.f,0.f};
      sf[fc] = __builtin_amdgcn_mfma_f32_16x16x32_f16(bfr[fc*2+0], aq[0], sf[fc], 0,0,0);
      sf[fc] = __builtin_amdgcn_mfma_f32_16x16x32_f16(bfr[fc*2+1], aq[1], sf[fc], 0,0,0);
    }

    // ---- batch-load S2's 10 R-frags ----
    {
      const _Float16* rp = RKC + (size_t)jv*64 + laneK;
#pragma unroll
      for (int i=0;i<10;i++)
        bfr[i] = *(const f16x8*)(rp + (i>>1)*1024 + (i&1)*32);
    }
    // ---- S2 (swapped): C[dgl][q]; store rows [q=lo][dgl] as u64 ----
#pragma unroll
    for (int dc=0;dc<5;dc++){
      f32x4 s2 = (f32x4){0.f,0.f,0.f,0.f};
      s2 = __builtin_amdgcn_mfma_f32_16x16x32_f16(bfr[dc*2+0], aq[0], s2, 0,0,0);
      s2 = __builtin_amdgcn_mfma_f32_16x16x32_f16(bfr[dc*2+1], aq[1], s2, 0,0,0);
      union { unsigned long long u; _Float16 h[4]; } tt;
#pragma unroll
      for (int r=0;r<4;r++) tt.h[r] = (_Float16)s2[r];
      *(u64a*)(smw + (unsigned)(lo*256) + (((unsigned)(dc*32 + hi*8)) ^ swz)) = tt.u;
    }

    // ---- T14 prefetch: PV's 8 V-frags issue now, consumed after softmax ----
    f16x8 bv[8];
    {
      const _Float16* vp = VTh + k0 + laneV;
#pragma unroll
      for (int i=0;i<8;i++)
        bv[i] = *(const f16x8*)(vp + (i>>1)*(16*S_LEN) + (i&1)*32);
    }

    // ---- bias add (same-wave LDS readback; may_alias keeps order vs stores) ----
    float mx = -1e30f;
#pragma unroll
    for (int fc=0;fc<4;fc++){
#pragma unroll
      for (int r=0;r<4;r++){
        const int kp2 = fc*16 + hi*4 + r;
        const int dgl = lo - kp2 + 63;
        const f16a hb = *(const f16a*)(smw + (unsigned)(lo*256) + (((unsigned)(dgl*2)) ^ swz));
        float v = sf[fc][r] + (float)hb;
        if (k0 + kp2 >= S_LEN) v = -1e30f;
        sf[fc][r] = v;
        mx = fmaxf(mx, v);
      }
    }

    // ---- W zero-fill (4KB); ordered after the bias reads (may-alias) ----
    {
      const u32x4a z = {0u,0u,0u,0u};
#pragma unroll
      for (int i=0;i<4;i++)
        *(u32x4a*)(smw + (unsigned)(i*1024 + lane*16)) = z;
    }

    // ---- softmax (base-2, lane-local row q=lo); V loads in flight under this ----
    mx = fmaxf(mx, __shfl_xor(mx,16));
    mx = fmaxf(mx, __shfl_xor(mx,32));
    const float mnew = fmaxf(m_run, mx);
    const float rr = exp2f(m_run - mnew);
    m_run = mnew;
    float sum = 0.f;
#pragma unroll
    for (int fc=0;fc<4;fc++){
#pragma unroll
      for (int r=0;r<4;r++){
        const float pv = exp2f(sf[fc][r] - mnew);
        sf[fc][r] = pv; sum += pv;
      }
    }
    sum += __shfl_xor(sum,16);
    sum += __shfl_xor(sum,32);
    l_run = l_run*rr + sum;

    // acc rescale: need rr at q = 4*hi + r
    {
      float rs0 = __shfl(rr, hi*4+0);
      float rs1 = __shfl(rr, hi*4+1);
      float rs2 = __shfl(rr, hi*4+2);
      float rs3 = __shfl(rr, hi*4+3);
#pragma unroll
      for (int fc=0;fc<4;fc++){
        acc[fc][0]*=rs0; acc[fc][1]*=rs1; acc[fc][2]*=rs2; acc[fc][3]*=rs3;
      }
    }

    // ---- scatter: P u64 rows, W scalar banded ----
#pragma unroll
    for (int fc=0;fc<4;fc++){
      union { unsigned long long u; _Float16 hh[4]; } tp;
#pragma unroll
      for (int r=0;r<4;r++) tp.hh[r] = (_Float16)sf[fc][r];
      *(u64a*)(smw + 4096u + (unsigned)(lo*128) + (((unsigned)(fc*32 + hi*8)) ^ swz)) = tp.u;
#pragma unroll
      for (int r=0;r<4;r++){
        const int kp2 = fc*16 + hi*4 + r;
        const int dgp = lo - kp2 + 63 + sh;
        *(f16a*)(smw + (unsigned)(lo*256) + (((unsigned)(dgp*2)) ^ swz)) = tp.hh[r];
      }
    }

    // ---- C4a: acc += P @ V^T (bv prefetched) ----
    f16x8 ap[2];
#pragma unroll
    for (int kk=0;kk<2;kk++)
      ap[kk] = *(const f16x8a*)(smw + 4096u + (unsigned)(lo*128) + (((unsigned)(kk*64 + hi*16)) ^ swz));
#pragma unroll
    for (int kk=0;kk<2;kk++){
#pragma unroll
      for (int fc=0;fc<4;fc++)
        acc[fc] = __builtin_amdgcn_mfma_f32_16x16x32_f16(ap[kk], bv[fc*2+kk], acc[fc], 0,0,0);
    }

    // ---- C4b: acc += W @ RvE^T (batch 4 frags per kk) ----
    const _Float16* rvp = RVC + jv8 + laneR;
#pragma unroll
    for (int kk=0;kk<3;kk++){
      f16x8 bw[4];
#pragma unroll
      for (int fc=0;fc<4;fc++)
        bw[fc] = *(const f16x8*)(rvp + fc*(16*1128) + kk*32);
      f16x8 aw = *(const f16x8a*)(smw + (unsigned)(lo*256) + (((unsigned)(kk*64 + hi*16)) ^ swz));
#pragma unroll
      for (int fc=0;fc<4;fc++)
        acc[fc] = __builtin_amdgcn_mfma_f32_16x16x32_f16(aw, bw[fc], acc[fc], 0,0,0);
    }
  }

  // ---- merge the two kt-halves within each (wq) pair ----
  if (wk == 1){
    // store into this wave's OWN region (loop done, region dead)
#pragma unroll
    for (int fc=0; fc<4; fc++)
#pragma unroll
      for (int r=0; r<4; r++)
        *(f32a*)(smw + (unsigned)((hi*4+r)*256 + (fc*16+lo)*4)) = acc[fc][r];
    if (hi == 0){
      *(f32a*)(smw + 4096u + (unsigned)(lo*8))     = m_run;
      *(f32a*)(smw + 4096u + (unsigned)(lo*8 + 4)) = l_run;
    }
  }
  __syncthreads();
  if (wk == 0){
    char* const pmw = smw + WAVE_LDS;   // partner (wk==1) region
    const float m1 = *(const f32a*)(pmw + 4096u + (unsigned)(lo*8));
    const float l1 = *(const f32a*)(pmw + 4096u + (unsigned)(lo*8 + 4));
    const float mm = fmaxf(m_run, m1);
    const float e0 = exp2f(m_run - mm);
    const float e1 = exp2f(m1 - mm);
    const float inv = 1.f / (l_run*e0 + l1*e1);
    const float f0 = e0*inv, f1 = e1*inv;
    float f0b[4], f1b[4];
#pragma unroll
    for (int r=0;r<4;r++){
      f0b[r] = __shfl(f0, hi*4+r);
      f1b[r] = __shfl(f1, hi*4+r);
    }
#pragma unroll
    for (int fc=0; fc<4; fc++)
#pragma unroll
      for (int r=0; r<4; r++){
        const int q = q0 + hi*4 + r;
        const float a1 = *(const f32a*)(pmw + (unsigned)((hi*4+r)*256 + (fc*16+lo)*4));
        if (q < S_LEN)
          Og[((size_t)b*S_LEN + q)*512 + h*DH + fc*16 + lo] =
              acc[fc][r]*f0b[r] + a1*f1b[r];
      }
  }
}

extern "C" void kernel_launch(void* const* d_in, const int* in_sizes, int n_in,
                              void* d_out, int out_size, void* d_ws, size_t ws_size,
                              hipStream_t stream) {
  (void)in_sizes; (void)n_in; (void)out_size; (void)ws_size;
  const float* Q  = (const float*)d_in[0];
  const float* K  = (const float*)d_in[1];
  const float* V  = (const float*)d_in[2];
  const float* RK = (const float*)d_in[3];
  const float* RV = (const float*)d_in[4];
  float* O = (float*)d_out;
  _Float16* ws = (_Float16*)d_ws;

  p_kv <<<dim3(1024), dim3(256), 0, stream>>>(K, V, ws);
  p_rel<<<dim3(18),   dim3(256), 0, stream>>>(RK, RV, ws);
  cra_attn<<<dim3(2048), dim3(256), 0, stream>>>(Q, ws, O);
}